// Round 1
// baseline (166.678 us; speedup 1.0000x reference)
//
#include <hip/hip_runtime.h>
#include <cmath>

// ---------------- problem constants ----------------
#define NS 32768
// output flat offsets (fp32 elements)
#define OUT1_BASE (NS * 256)                 // 8388608
#define OUT2_BASE (OUT1_BASE + NS * 576)     // 27262976
#define OUT3_BASE (OUT2_BASE + NS * 640)     // 48234496

// ---------------- host-side U construction (port of reference) ----------------
namespace {

static double hfact(int n) { double r = 1.0; for (int i = 2; i <= n; ++i) r *= (double)i; return r; }

static double cg_coeff(int j1, int m1, int j2, int m2, int J, int M) {
    if (m1 + m2 != M) return 0.0;
    double pref = (2.0 * J + 1.0) * hfact(j1 + j2 - J) * hfact(j1 - j2 + J)
                * hfact(-j1 + j2 + J) / hfact(j1 + j2 + J + 1);
    pref *= hfact(J + M) * hfact(J - M) * hfact(j1 - m1) * hfact(j1 + m1)
          * hfact(j2 - m2) * hfact(j2 + m2);
    int kmin = 0;
    if (j2 - J - m1 > kmin) kmin = j2 - J - m1;
    if (j1 + m2 - J > kmin) kmin = j1 + m2 - J;
    int kmax = j1 + j2 - J;
    if (j1 - m1 < kmax) kmax = j1 - m1;
    if (j2 + m2 < kmax) kmax = j2 + m2;
    double s = 0.0;
    for (int k = kmin; k <= kmax; ++k) {
        double d = hfact(k) * hfact(j1 + j2 - J - k) * hfact(j1 - m1 - k)
                 * hfact(j2 + m2 - k) * hfact(J - j2 + m1 + k) * hfact(J - j1 - m2 + k);
        s += ((k & 1) ? -1.0 : 1.0) / d;
    }
    return std::sqrt(pref) * s;
}

struct C2 { double re, im; };
static inline C2 cmul(C2 a, C2 b) { return { a.re * b.re - a.im * b.im, a.re * b.im + a.im * b.re }; }
static inline C2 cadd(C2 a, C2 b) { return { a.re + b.re, a.im + b.im }; }
static inline C2 cscale(C2 a, double s) { return { a.re * s, a.im * s }; }
static inline C2 conjc(C2 a) { return { a.re, -a.im }; }

// R: (2L+1)x(2L+1) row-major; R[complex_row * D + real_col]
static void real2complex(int L, C2* R) {
    int D = 2 * L + 1;
    for (int i = 0; i < D * D; ++i) R[i] = { 0.0, 0.0 };
    double isq2 = 1.0 / std::sqrt(2.0);
    for (int m = -L; m <= L; ++m) {
        double sgn = (m & 1) ? -1.0 : 1.0;   // (-1)^m (parity; works for negative m)
        if (m < 0) {
            R[(L - m) * D + (L + m)] = { 0.0, isq2 * sgn };
            R[(L + m) * D + (L + m)] = { 0.0, -isq2 };
        } else if (m == 0) {
            R[L * D + L] = { 1.0, 0.0 };
        } else {
            R[(L - m) * D + (L + m)] = { isq2, 0.0 };
            R[(L + m) * D + (L + m)] = { isq2 * sgn, 0.0 };
        }
    }
}

// out: (2l1+1)x(2l2+1)x(2L+1) real doubles
static void cg_real(int l1, int l2, int L, double* out) {
    int D1 = 2 * l1 + 1, D2 = 2 * l2 + 1, DL = 2 * L + 1;
    double ccg[5 * 5 * 9];
    for (int i = 0; i < D1 * D2 * DL; ++i) ccg[i] = 0.0;
    for (int m1 = -l1; m1 <= l1; ++m1)
        for (int m2 = -l2; m2 <= l2; ++m2) {
            int M = m1 + m2;
            if (M >= -L && M <= L)
                ccg[((m1 + l1) * D2 + (m2 + l2)) * DL + (M + L)] = cg_coeff(l1, m1, l2, m2, L, M);
        }
    C2 R1[5 * 5], R2[5 * 5], RL[9 * 9];
    real2complex(l1, R1);
    real2complex(l2, R2);
    real2complex(L, RL);
    bool even = ((l1 + l2 + L) % 2) == 0;
    for (int a = 0; a < D1; ++a)
        for (int b = 0; b < D2; ++b) {
            C2 tmp[9];
            for (int M = 0; M < DL; ++M) {
                C2 s = { 0.0, 0.0 };
                for (int m = 0; m < D1; ++m)
                    for (int n = 0; n < D2; ++n) {
                        double c = ccg[(m * D2 + n) * DL + M];
                        if (c != 0.0)
                            s = cadd(s, cscale(cmul(R1[m * D1 + a], R2[n * D2 + b]), c));
                    }
                tmp[M] = s;
            }
            for (int k = 0; k < DL; ++k) {
                C2 s = { 0.0, 0.0 };
                for (int M = 0; M < DL; ++M)
                    s = cadd(s, cmul(tmp[M], conjc(RL[M * DL + k])));
                out[(a * D2 + b) * DL + k] = even ? s.re : s.im;
            }
        }
}

// U for padded pl (even): ((pl+1)^2) x ((pl+1)^2), row = a*(pl+1)+b, col = concat(L,m)
static void build_U(int pl, float* U) {
    int h = pl / 2, P = pl + 1, DU = P * P;
    int off = 0;
    for (int L = 0; L <= pl; ++L) {
        int DL = 2 * L + 1;
        double blk[5 * 5 * 9];
        cg_real(h, h, L, blk);
        for (int a = 0; a < P; ++a)
            for (int b = 0; b < P; ++b)
                for (int k = 0; k < DL; ++k)
                    U[(a * P + b) * DU + (off + k)] = (float)blk[(a * P + b) * DL + k];
        off += DL;
    }
}

} // namespace

// ---------------- device kernels ----------------

struct U9Arg  { float u[81];  };
struct U25Arg { float u[625]; };

// band 0: pl=0 -> elementwise product of channels 192:256 of f_0 -> out_0[:, :, 0:64]
__global__ __launch_bounds__(256) void band0_kernel(
    const float* __restrict__ f1_0, const float* __restrict__ f2_0,
    float* __restrict__ out)
{
    int t = blockIdx.x * 256 + threadIdx.x;
    int n = t >> 6, c = t & 63;
    int idx = n * 256 + 192 + c;
    out[n * 256 + c] = f1_0[idx] * f2_0[idx];
}

// band 1: pl=2, inputs = channels 128:192 of f_0,f_1 (4 real entries of 9);
// only output blocks L=0 (-> out_0 ch 64:128) and L=1 (-> out_1 ch 0:64) survive.
__global__ __launch_bounds__(256) void band1_kernel(
    const float* __restrict__ f1_0, const float* __restrict__ f1_1,
    const float* __restrict__ f2_0, const float* __restrict__ f2_1,
    float* __restrict__ out, U9Arg U)
{
    int t = blockIdx.x * 256 + threadIdx.x;
    int n = t >> 6, c = t & 63;
    int ch = 128 + c;

    float x1[4], x2[4];
    x1[0] = f1_0[n * 256 + ch];
    x2[0] = f2_0[n * 256 + ch];
#pragma unroll
    for (int m = 0; m < 3; ++m) {
        x1[1 + m] = f1_1[n * 576 + m * 192 + ch];
        x2[1 + m] = f2_1[n * 576 + m * 192 + ch];
    }

    float A[9], B[9];
#pragma unroll
    for (int M = 0; M < 9; ++M) {
        float sa = 0.f, sb = 0.f;
#pragma unroll
        for (int N = 0; N < 4; ++N) { sa += U.u[M * 9 + N] * x1[N]; sb += U.u[M * 9 + N] * x2[N]; }
        A[M] = sa; B[M] = sb;
    }

    float C[9];
#pragma unroll
    for (int i = 0; i < 3; ++i)
#pragma unroll
        for (int k = 0; k < 3; ++k) {
            float s = 0.f;
#pragma unroll
            for (int j = 0; j < 3; ++j) s += A[i * 3 + j] * B[j * 3 + k];
            C[i * 3 + k] = s;
        }

    float y[4];
#pragma unroll
    for (int M = 0; M < 4; ++M) {
        float s = 0.f;
#pragma unroll
        for (int N = 0; N < 9; ++N) s += U.u[N * 9 + M] * C[N];
        y[M] = s;
    }

    out[n * 256 + 64 + c] = y[0];
#pragma unroll
    for (int m = 0; m < 3; ++m)
        out[OUT1_BASE + n * 576 + m * 192 + c] = y[1 + m];
}

// band 2: pl=2, inputs = channels 64:128 of f_0,f_1,f_2 (all 9 entries);
// outputs L=0 -> out_0 ch 128:192, L=1 -> out_1 ch 64:128, L=2 -> out_2 ch 0:64.
__global__ __launch_bounds__(256) void band2_kernel(
    const float* __restrict__ f1_0, const float* __restrict__ f1_1, const float* __restrict__ f1_2,
    const float* __restrict__ f2_0, const float* __restrict__ f2_1, const float* __restrict__ f2_2,
    float* __restrict__ out, U9Arg U)
{
    int t = blockIdx.x * 256 + threadIdx.x;
    int n = t >> 6, c = t & 63;
    int ch = 64 + c;

    float x1[9], x2[9];
    x1[0] = f1_0[n * 256 + ch];
    x2[0] = f2_0[n * 256 + ch];
#pragma unroll
    for (int m = 0; m < 3; ++m) {
        x1[1 + m] = f1_1[n * 576 + m * 192 + ch];
        x2[1 + m] = f2_1[n * 576 + m * 192 + ch];
    }
#pragma unroll
    for (int m = 0; m < 5; ++m) {
        x1[4 + m] = f1_2[n * 640 + m * 128 + ch];
        x2[4 + m] = f2_2[n * 640 + m * 128 + ch];
    }

    float A[9], B[9];
#pragma unroll
    for (int M = 0; M < 9; ++M) {
        float sa = 0.f, sb = 0.f;
#pragma unroll
        for (int N = 0; N < 9; ++N) { sa += U.u[M * 9 + N] * x1[N]; sb += U.u[M * 9 + N] * x2[N]; }
        A[M] = sa; B[M] = sb;
    }

    float C[9];
#pragma unroll
    for (int i = 0; i < 3; ++i)
#pragma unroll
        for (int k = 0; k < 3; ++k) {
            float s = 0.f;
#pragma unroll
            for (int j = 0; j < 3; ++j) s += A[i * 3 + j] * B[j * 3 + k];
            C[i * 3 + k] = s;
        }

    float y[9];
#pragma unroll
    for (int M = 0; M < 9; ++M) {
        float s = 0.f;
#pragma unroll
        for (int N = 0; N < 9; ++N) s += U.u[N * 9 + M] * C[N];
        y[M] = s;
    }

    out[n * 256 + 128 + c] = y[0];
#pragma unroll
    for (int m = 0; m < 3; ++m)
        out[OUT1_BASE + n * 576 + m * 192 + 64 + c] = y[1 + m];
#pragma unroll
    for (int m = 0; m < 5; ++m)
        out[OUT2_BASE + n * 640 + m * 128 + c] = y[4 + m];
}

// band 3: pl=4, inputs = channels 0:64 of f_0..f_3 (16 real entries of 25);
// outputs L=0..3 (L=4 block discarded).
__global__ __launch_bounds__(256) void band3_kernel(
    const float* __restrict__ f1_0, const float* __restrict__ f1_1,
    const float* __restrict__ f1_2, const float* __restrict__ f1_3,
    const float* __restrict__ f2_0, const float* __restrict__ f2_1,
    const float* __restrict__ f2_2, const float* __restrict__ f2_3,
    float* __restrict__ out, U25Arg U)
{
    int t = blockIdx.x * 256 + threadIdx.x;
    int n = t >> 6, c = t & 63;

    float x1[16], x2[16];
    x1[0] = f1_0[n * 256 + c];
    x2[0] = f2_0[n * 256 + c];
#pragma unroll
    for (int m = 0; m < 3; ++m) {
        x1[1 + m] = f1_1[n * 576 + m * 192 + c];
        x2[1 + m] = f2_1[n * 576 + m * 192 + c];
    }
#pragma unroll
    for (int m = 0; m < 5; ++m) {
        x1[4 + m] = f1_2[n * 640 + m * 128 + c];
        x2[4 + m] = f2_2[n * 640 + m * 128 + c];
    }
#pragma unroll
    for (int m = 0; m < 7; ++m) {
        x1[9 + m] = f1_3[n * 448 + m * 64 + c];
        x2[9 + m] = f2_3[n * 448 + m * 64 + c];
    }

    float A[25], B[25];
#pragma unroll
    for (int M = 0; M < 25; ++M) {
        float sa = 0.f, sb = 0.f;
#pragma unroll
        for (int N = 0; N < 16; ++N) { sa += U.u[M * 25 + N] * x1[N]; sb += U.u[M * 25 + N] * x2[N]; }
        A[M] = sa; B[M] = sb;
    }

    float C[25];
#pragma unroll
    for (int i = 0; i < 5; ++i)
#pragma unroll
        for (int k = 0; k < 5; ++k) {
            float s = 0.f;
#pragma unroll
            for (int j = 0; j < 5; ++j) s += A[i * 5 + j] * B[j * 5 + k];
            C[i * 5 + k] = s;
        }

    float y[16];
#pragma unroll
    for (int M = 0; M < 16; ++M) {
        float s = 0.f;
#pragma unroll
        for (int N = 0; N < 25; ++N) s += U.u[N * 25 + M] * C[N];
        y[M] = s;
    }

    out[n * 256 + 192 + c] = y[0];
#pragma unroll
    for (int m = 0; m < 3; ++m)
        out[OUT1_BASE + n * 576 + m * 192 + 128 + c] = y[1 + m];
#pragma unroll
    for (int m = 0; m < 5; ++m)
        out[OUT2_BASE + n * 640 + m * 128 + 64 + c] = y[4 + m];
#pragma unroll
    for (int m = 0; m < 7; ++m)
        out[OUT3_BASE + n * 448 + m * 64 + c] = y[9 + m];
}

// ---------------- launch ----------------
extern "C" void kernel_launch(void* const* d_in, const int* in_sizes, int n_in,
                              void* d_out, int out_size, void* d_ws, size_t ws_size,
                              hipStream_t stream)
{
    U9Arg U9;
    U25Arg U25;
    build_U(2, U9.u);
    build_U(4, U25.u);

    const float* f1_0 = (const float*)d_in[0];
    const float* f1_1 = (const float*)d_in[1];
    const float* f1_2 = (const float*)d_in[2];
    const float* f1_3 = (const float*)d_in[3];
    const float* f2_0 = (const float*)d_in[4];
    const float* f2_1 = (const float*)d_in[5];
    const float* f2_2 = (const float*)d_in[6];
    const float* f2_3 = (const float*)d_in[7];
    float* out = (float*)d_out;

    dim3 blk(256);
    dim3 grid(NS / 4);   // 4 samples per block, lane = channel (64)

    band0_kernel<<<grid, blk, 0, stream>>>(f1_0, f2_0, out);
    band1_kernel<<<grid, blk, 0, stream>>>(f1_0, f1_1, f2_0, f2_1, out, U9);
    band2_kernel<<<grid, blk, 0, stream>>>(f1_0, f1_1, f1_2, f2_0, f2_1, f2_2, out, U9);
    band3_kernel<<<grid, blk, 0, stream>>>(f1_0, f1_1, f1_2, f1_3, f2_0, f2_1, f2_2, f2_3, out, U25);
}

// Round 2
// 143.016 us; speedup vs baseline: 1.1654x; 1.1654x over previous
//
#include <hip/hip_runtime.h>

// ---------------- problem constants ----------------
#define NS 32768
// output flat offsets (fp32 elements)
#define OUT1_BASE (NS * 256)                 // 8388608
#define OUT2_BASE (OUT1_BASE + NS * 576)     // 27262976
#define OUT3_BASE (OUT2_BASE + NS * 640)     // 48234496

// ================= compile-time U construction =================
// Full constexpr port of the reference CG build. Split into per-(pl,L)
// constexpr variables so each initializer stays well under clang's
// per-evaluation constexpr step limit.
namespace cgc {

constexpr double hfact(int n) { double r = 1.0; for (int i = 2; i <= n; ++i) r *= (double)i; return r; }

constexpr double csqrt(double a) {
    if (a <= 0.0) return 0.0;
    double x = a > 1.0 ? a : 1.0;
    for (int i = 0; i < 64; ++i) x = 0.5 * (x + a / x);
    return x;
}

constexpr double cg_coeff(int j1, int m1, int j2, int m2, int J, int M) {
    if (m1 + m2 != M) return 0.0;
    double pref = (2.0 * J + 1.0) * hfact(j1 + j2 - J) * hfact(j1 - j2 + J)
                * hfact(-j1 + j2 + J) / hfact(j1 + j2 + J + 1);
    pref *= hfact(J + M) * hfact(J - M) * hfact(j1 - m1) * hfact(j1 + m1)
          * hfact(j2 - m2) * hfact(j2 + m2);
    int kmin = 0;
    if (j2 - J - m1 > kmin) kmin = j2 - J - m1;
    if (j1 + m2 - J > kmin) kmin = j1 + m2 - J;
    int kmax = j1 + j2 - J;
    if (j1 - m1 < kmax) kmax = j1 - m1;
    if (j2 + m2 < kmax) kmax = j2 + m2;
    double s = 0.0;
    for (int k = kmin; k <= kmax; ++k) {
        double d = hfact(k) * hfact(j1 + j2 - J - k) * hfact(j1 - m1 - k)
                 * hfact(j2 + m2 - k) * hfact(J - j2 + m1 + k) * hfact(J - j1 - m2 + k);
        s += ((k & 1) ? -1.0 : 1.0) / d;
    }
    return csqrt(pref) * s;
}

struct C2 { double re; double im; };
constexpr C2 cmul(C2 a, C2 b) { return { a.re * b.re - a.im * b.im, a.re * b.im + a.im * b.re }; }
constexpr C2 cadd(C2 a, C2 b) { return { a.re + b.re, a.im + b.im }; }
constexpr C2 cscale(C2 a, double s) { return { a.re * s, a.im * s }; }
constexpr C2 conjc(C2 a) { return { a.re, -a.im }; }

struct R2C { C2 r[81]; };   // up to 9x9, stride D = 2L+1

constexpr R2C real2complex(int L) {
    R2C R{};
    int D = 2 * L + 1;
    double isq2 = 0.70710678118654752440084436210485;  // 1/sqrt(2), exact algorithm uses 1/sqrt(2)
    // use csqrt for bit-compat with reference-ish; value identical to literal above
    isq2 = 1.0 / csqrt(2.0);
    for (int m = -L; m <= L; ++m) {
        double sgn = (m & 1) ? -1.0 : 1.0;   // (-1)^m
        if (m < 0) {
            R.r[(L - m) * D + (L + m)] = { 0.0, isq2 * sgn };
            R.r[(L + m) * D + (L + m)] = { 0.0, -isq2 };
        } else if (m == 0) {
            R.r[L * D + L] = { 1.0, 0.0 };
        } else {
            R.r[(L - m) * D + (L + m)] = { isq2, 0.0 };
            R.r[(L + m) * D + (L + m)] = { isq2 * sgn, 0.0 };
        }
    }
    return R;
}

struct Blk { double v[225]; };  // (2l1+1)*(2l2+1)*(2L+1) max = 5*5*9

constexpr Blk cg_real(int l1, int l2, int L) {
    Blk out{};
    int D1 = 2 * l1 + 1, D2 = 2 * l2 + 1, DL = 2 * L + 1;
    double ccg[225] = {};
    for (int m1 = -l1; m1 <= l1; ++m1)
        for (int m2 = -l2; m2 <= l2; ++m2) {
            int M = m1 + m2;
            if (M >= -L && M <= L)
                ccg[((m1 + l1) * D2 + (m2 + l2)) * DL + (M + L)] = cg_coeff(l1, m1, l2, m2, L, M);
        }
    R2C R1 = real2complex(l1);
    R2C R2 = real2complex(l2);
    R2C RL = real2complex(L);
    bool even = ((l1 + l2 + L) % 2) == 0;
    for (int a = 0; a < D1; ++a)
        for (int b = 0; b < D2; ++b) {
            C2 tmp[9] = {};
            for (int M = 0; M < DL; ++M) {
                C2 s = { 0.0, 0.0 };
                for (int m = 0; m < D1; ++m)
                    for (int nn = 0; nn < D2; ++nn) {
                        double cc = ccg[(m * D2 + nn) * DL + M];
                        if (cc != 0.0)
                            s = cadd(s, cscale(cmul(R1.r[m * D1 + a], R2.r[nn * D2 + b]), cc));
                    }
                tmp[M] = s;
            }
            for (int k = 0; k < DL; ++k) {
                C2 s = { 0.0, 0.0 };
                for (int M = 0; M < DL; ++M)
                    s = cadd(s, cmul(tmp[M], conjc(RL.r[M * DL + k])));
                out.v[(a * D2 + b) * DL + k] = even ? s.re : s.im;
            }
        }
    return out;
}

// separate constexpr evaluations (step-limit safety)
constexpr Blk B2_0 = cg_real(1, 1, 0);
constexpr Blk B2_1 = cg_real(1, 1, 1);
constexpr Blk B2_2 = cg_real(1, 1, 2);
constexpr Blk B4_0 = cg_real(2, 2, 0);
constexpr Blk B4_1 = cg_real(2, 2, 1);
constexpr Blk B4_2 = cg_real(2, 2, 2);
constexpr Blk B4_3 = cg_real(2, 2, 3);
constexpr Blk B4_4 = cg_real(2, 2, 4);

struct U9T  { float u[81];  };
struct U25T { float u[625]; };

constexpr U9T build_U9() {
    U9T U{};
    const Blk* bl[3] = { &B2_0, &B2_1, &B2_2 };
    int off = 0;
    for (int L = 0; L <= 2; ++L) {
        int DL = 2 * L + 1;
        for (int a = 0; a < 3; ++a)
            for (int b = 0; b < 3; ++b)
                for (int k = 0; k < DL; ++k)
                    U.u[(a * 3 + b) * 9 + (off + k)] = (float)bl[L]->v[(a * 3 + b) * DL + k];
        off += DL;
    }
    return U;
}

constexpr U25T build_U25() {
    U25T U{};
    const Blk* bl[5] = { &B4_0, &B4_1, &B4_2, &B4_3, &B4_4 };
    int off = 0;
    for (int L = 0; L <= 4; ++L) {
        int DL = 2 * L + 1;
        for (int a = 0; a < 5; ++a)
            for (int b = 0; b < 5; ++b)
                for (int k = 0; k < DL; ++k)
                    U.u[(a * 5 + b) * 25 + (off + k)] = (float)bl[L]->v[(a * 5 + b) * DL + k];
        off += DL;
    }
    return U;
}

constexpr U9T  U9c  = build_U9();
constexpr U25T U25c = build_U25();

} // namespace cgc

// ================= fused device kernel =================
// One thread = (sample n, channel c in 0..63). Does all four bands.
// All multiplies against U are guarded by compile-time `!= 0` tests so the
// compiler prunes structural zeros after full unroll.

__global__ __launch_bounds__(256) void tp_fused_kernel(
    const float* __restrict__ f1_0, const float* __restrict__ f1_1,
    const float* __restrict__ f1_2, const float* __restrict__ f1_3,
    const float* __restrict__ f2_0, const float* __restrict__ f2_1,
    const float* __restrict__ f2_2, const float* __restrict__ f2_3,
    float* __restrict__ out)
{
    using namespace cgc;
    const int t = blockIdx.x * 256 + threadIdx.x;
    const int n = t >> 6, c = t & 63;
    const int r0 = n * 256, r1 = n * 576, r2 = n * 640, r3 = n * 448;

    // ---------- band 0 (pl=0): elementwise, f_0 ch 192:256 -> out_0 ch 0:64 ----------
    out[r0 + c] = f1_0[r0 + 192 + c] * f2_0[r0 + 192 + c];

    // ---------- band 1 (pl=2): f_0,f_1 ch 128:192; outputs L=0,1 ----------
    {
        const int ch = 128 + c;
        float x1[4], x2[4];
        x1[0] = f1_0[r0 + ch];
        x2[0] = f2_0[r0 + ch];
#pragma unroll
        for (int m = 0; m < 3; ++m) {
            x1[1 + m] = f1_1[r1 + m * 192 + ch];
            x2[1 + m] = f2_1[r1 + m * 192 + ch];
        }
        float A[9], B[9];
#pragma unroll
        for (int M = 0; M < 9; ++M) {
            float sa = 0.f, sb = 0.f;
#pragma unroll
            for (int N = 0; N < 4; ++N)
                if (U9c.u[M * 9 + N] != 0.0f) {
                    sa += U9c.u[M * 9 + N] * x1[N];
                    sb += U9c.u[M * 9 + N] * x2[N];
                }
            A[M] = sa; B[M] = sb;
        }
        float C[9];
#pragma unroll
        for (int i = 0; i < 3; ++i)
#pragma unroll
            for (int k = 0; k < 3; ++k) {
                float s = 0.f;
#pragma unroll
                for (int j = 0; j < 3; ++j) s += A[i * 3 + j] * B[j * 3 + k];
                C[i * 3 + k] = s;
            }
        float y[4];
#pragma unroll
        for (int M = 0; M < 4; ++M) {
            float s = 0.f;
#pragma unroll
            for (int N = 0; N < 9; ++N)
                if (U9c.u[N * 9 + M] != 0.0f) s += U9c.u[N * 9 + M] * C[N];
            y[M] = s;
        }
        out[r0 + 64 + c] = y[0];
#pragma unroll
        for (int m = 0; m < 3; ++m)
            out[OUT1_BASE + r1 + m * 192 + c] = y[1 + m];
    }

    // ---------- band 2 (pl=2): f_0..f_2 ch 64:128; outputs L=0,1,2 ----------
    {
        const int ch = 64 + c;
        float x1[9], x2[9];
        x1[0] = f1_0[r0 + ch];
        x2[0] = f2_0[r0 + ch];
#pragma unroll
        for (int m = 0; m < 3; ++m) {
            x1[1 + m] = f1_1[r1 + m * 192 + ch];
            x2[1 + m] = f2_1[r1 + m * 192 + ch];
        }
#pragma unroll
        for (int m = 0; m < 5; ++m) {
            x1[4 + m] = f1_2[r2 + m * 128 + ch];
            x2[4 + m] = f2_2[r2 + m * 128 + ch];
        }
        float A[9], B[9];
#pragma unroll
        for (int M = 0; M < 9; ++M) {
            float sa = 0.f, sb = 0.f;
#pragma unroll
            for (int N = 0; N < 9; ++N)
                if (U9c.u[M * 9 + N] != 0.0f) {
                    sa += U9c.u[M * 9 + N] * x1[N];
                    sb += U9c.u[M * 9 + N] * x2[N];
                }
            A[M] = sa; B[M] = sb;
        }
        float C[9];
#pragma unroll
        for (int i = 0; i < 3; ++i)
#pragma unroll
            for (int k = 0; k < 3; ++k) {
                float s = 0.f;
#pragma unroll
                for (int j = 0; j < 3; ++j) s += A[i * 3 + j] * B[j * 3 + k];
                C[i * 3 + k] = s;
            }
        float y[9];
#pragma unroll
        for (int M = 0; M < 9; ++M) {
            float s = 0.f;
#pragma unroll
            for (int N = 0; N < 9; ++N)
                if (U9c.u[N * 9 + M] != 0.0f) s += U9c.u[N * 9 + M] * C[N];
            y[M] = s;
        }
        out[r0 + 128 + c] = y[0];
#pragma unroll
        for (int m = 0; m < 3; ++m)
            out[OUT1_BASE + r1 + m * 192 + 64 + c] = y[1 + m];
#pragma unroll
        for (int m = 0; m < 5; ++m)
            out[OUT2_BASE + r2 + m * 128 + c] = y[4 + m];
    }

    // ---------- band 3 (pl=4): f_0..f_3 ch 0:64; outputs L=0..3 ----------
    {
        float x1[16], x2[16];
        x1[0] = f1_0[r0 + c];
        x2[0] = f2_0[r0 + c];
#pragma unroll
        for (int m = 0; m < 3; ++m) {
            x1[1 + m] = f1_1[r1 + m * 192 + c];
            x2[1 + m] = f2_1[r1 + m * 192 + c];
        }
#pragma unroll
        for (int m = 0; m < 5; ++m) {
            x1[4 + m] = f1_2[r2 + m * 128 + c];
            x2[4 + m] = f2_2[r2 + m * 128 + c];
        }
#pragma unroll
        for (int m = 0; m < 7; ++m) {
            x1[9 + m] = f1_3[r3 + m * 64 + c];
            x2[9 + m] = f2_3[r3 + m * 64 + c];
        }
        float A[25], B[25];
#pragma unroll
        for (int M = 0; M < 25; ++M) {
            float sa = 0.f, sb = 0.f;
#pragma unroll
            for (int N = 0; N < 16; ++N)
                if (U25c.u[M * 25 + N] != 0.0f) {
                    sa += U25c.u[M * 25 + N] * x1[N];
                    sb += U25c.u[M * 25 + N] * x2[N];
                }
            A[M] = sa; B[M] = sb;
        }
        float C[25];
#pragma unroll
        for (int i = 0; i < 5; ++i)
#pragma unroll
            for (int k = 0; k < 5; ++k) {
                float s = 0.f;
#pragma unroll
                for (int j = 0; j < 5; ++j) s += A[i * 5 + j] * B[j * 5 + k];
                C[i * 5 + k] = s;
            }
        float y[16];
#pragma unroll
        for (int M = 0; M < 16; ++M) {
            float s = 0.f;
#pragma unroll
            for (int N = 0; N < 25; ++N)
                if (U25c.u[N * 25 + M] != 0.0f) s += U25c.u[N * 25 + M] * C[N];
            y[M] = s;
        }
        out[r0 + 192 + c] = y[0];
#pragma unroll
        for (int m = 0; m < 3; ++m)
            out[OUT1_BASE + r1 + m * 192 + 128 + c] = y[1 + m];
#pragma unroll
        for (int m = 0; m < 5; ++m)
            out[OUT2_BASE + r2 + m * 128 + 64 + c] = y[4 + m];
#pragma unroll
        for (int m = 0; m < 7; ++m)
            out[OUT3_BASE + r3 + m * 64 + c] = y[9 + m];
    }
}

// ---------------- launch ----------------
extern "C" void kernel_launch(void* const* d_in, const int* in_sizes, int n_in,
                              void* d_out, int out_size, void* d_ws, size_t ws_size,
                              hipStream_t stream)
{
    const float* f1_0 = (const float*)d_in[0];
    const float* f1_1 = (const float*)d_in[1];
    const float* f1_2 = (const float*)d_in[2];
    const float* f1_3 = (const float*)d_in[3];
    const float* f2_0 = (const float*)d_in[4];
    const float* f2_1 = (const float*)d_in[5];
    const float* f2_2 = (const float*)d_in[6];
    const float* f2_3 = (const float*)d_in[7];
    float* out = (float*)d_out;

    dim3 blk(256);
    dim3 grid(NS / 4);   // 4 samples/block, lane = channel

    tp_fused_kernel<<<grid, blk, 0, stream>>>(f1_0, f1_1, f1_2, f1_3,
                                              f2_0, f2_1, f2_2, f2_3, out);
}